// Round 1
// baseline (170.297 us; speedup 1.0000x reference)
//
#include <hip/hip_runtime.h>

#define DEVFN __device__ __forceinline__

DEVFN float fast_rcp(float x) { return __builtin_amdgcn_rcpf(x); }

DEVFN float fast_tanh(float x) {
    // tanh(x) = 1 - 2/(exp(2x)+1); stable at both tails.
    float e = __expf(2.0f * x);
    return 1.0f - 2.0f * fast_rcp(e + 1.0f);
}

DEVFN float fast_asinh(float z) {
    float az = fabsf(z);
    float r = __logf(az + sqrtf(fmaf(az, az, 1.0f)));
    return copysignf(r, z);
}

__global__ __launch_bounds__(256) void battery_step_kernel(
    const float* __restrict__ inputs,   // (B,1)
    const float* __restrict__ states,   // (B,8)
    const float* __restrict__ qMax,     // (B,)
    const float* __restrict__ Ro,       // (B,)
    const float* __restrict__ tDiff,    // scalar
    const float* __restrict__ Wp1,      // (1,8)
    const float* __restrict__ bp1,      // (8,)
    const float* __restrict__ Wp2,      // (8,4)
    const float* __restrict__ bp2,      // (4,)
    const float* __restrict__ Wp3,      // (4,1)
    const float* __restrict__ bp3,      // (1,)
    const float* __restrict__ Wn,       // (1,1)
    const float* __restrict__ bn,       // (1,)
    float* __restrict__ outV,           // (B,)
    float* __restrict__ outX,           // (B,8)
    int n)
{
    int idx = blockIdx.x * 256 + threadIdx.x;
    if (idx >= n) return;

    // ---- coalesced vector loads: 32B of state per thread ----
    const float4 s0 = ((const float4*)states)[idx * 2 + 0];
    const float4 s1 = ((const float4*)states)[idx * 2 + 1];
    const float Tb = s0.x, Vo = s0.y, Vsn = s0.z, Vsp = s0.w;
    const float qnB = s1.x, qnS = s1.y, qpB = s1.z, qpS = s1.w;
    const float i  = inputs[idx];
    const float qm = qMax[idx];
    const float ro = Ro[idx];
    const float tD = tDiff[0];   // uniform -> scalar load

    // constants
    const float invVOLB = 1.0f / 1.98e-5f;   // VOLB = VOL - VOLS
    const float invVOLS = 1.0f / 2.2e-6f;    // VOLS = 0.1*VOL
    const float RTFA    = 8.3144621f / 96487.0f / 0.5f;  // R/F/alpha
    const float RF      = 8.3144621f / 96487.0f;         // R/F

    // qSMax = qMax * 10000 * (VOLS/VOL = 0.1) = qMax*1000
    const float qSMax = qm * 1000.0f;
    const float rq    = fast_rcp(qSMax);

    float xpS = fminf(fmaxf(qpS * rq, 1e-18f), 1.0f);
    float xnS = fminf(fmaxf(qnS * rq, 1e-18f), 1.0f);

    float Jn0 = 1e-18f + 20000.0f * sqrtf((1.0f - xnS) * xnS);
    float Jp0 = 1e-18f + 20000.0f * sqrtf((1.0f - xpS) * xpS);

    const float invTD = fast_rcp(tD);
    float qdotn = (qnB * invVOLB - qnS * invVOLS) * invTD;
    float qdotp = (qpB * invVOLB - qpS * invVOLS) * invTD;

    float Vodot = (i * ro * 10.0f - Vo) * 0.1f;  // RO_BASE=10, TO=10

    // i/SN/(2*J0) = i * 2500 / J0   (SN = SP = 2e-4)
    float zn = i * 2500.0f * fast_rcp(Jn0);
    float zp = i * 2500.0f * fast_rcp(Jp0);
    float VsnNom = RTFA * Tb * fast_asinh(zn);
    float VspNom = RTFA * Tb * fast_asinh(zp);
    float Vsndot = (VsnNom - Vsn) * (1.0f / 90.0f);
    float Vspdot = (VspNom - Vsp) * (1.0f / 90.0f);

    // state update (DT = 1)
    const float X0 = Tb;
    const float X1 = Vo + Vodot;
    const float X2 = Vsn + Vsndot;
    const float X3 = Vsp + Vspdot;
    const float X4 = qnB - qdotn;
    const float X5 = qnS + (qdotn - i);
    const float X6 = qpB - qdotp;
    const float X7 = qpS + (i + qdotp);

    const float xp2 = X7 * rq;
    const float xn2 = X5 * rq;

    // ---- tiny MLP (weights hit scalar cache) ----
    float h1[8];
#pragma unroll
    for (int j = 0; j < 8; ++j)
        h1[j] = fast_tanh(fmaf(xp2, Wp1[j], bp1[j]));

    float h2[4];
#pragma unroll
    for (int k = 0; k < 4; ++k) {
        float acc = bp2[k];
#pragma unroll
        for (int j = 0; j < 8; ++j)
            acc = fmaf(h1[j], Wp2[j * 4 + k], acc);
        h2[k] = fast_tanh(acc);
    }

    float VepMLP = bp3[0];
#pragma unroll
    for (int k = 0; k < 4; ++k)
        VepMLP = fmaf(h2[k], Wp3[k], VepMLP);

    const float VenMLP = fmaf(xn2, Wn[0], bn[0]);

    float slp = fminf(fmaxf((1.0f - xp2) * fast_rcp(xp2), 1e-18f), 1e18f);
    float sln = fminf(fmaxf((1.0f - xn2) * fast_rcp(xn2), 1e-18f), 1e18f);

    float Vep = 4.03f + RF * X0 * __logf(slp) + VepMLP;
    float Ven = 0.01f + RF * X0 * __logf(sln) + VenMLP;
    float V   = Vep - Ven - X1 - X2 - X3;

    // ---- coalesced stores ----
    outV[idx] = V;
    ((float4*)outX)[idx * 2 + 0] = make_float4(X0, X1, X2, X3);
    ((float4*)outX)[idx * 2 + 1] = make_float4(X4, X5, X6, X7);
}

extern "C" void kernel_launch(void* const* d_in, const int* in_sizes, int n_in,
                              void* d_out, int out_size, void* d_ws, size_t ws_size,
                              hipStream_t stream) {
    const float* inputs = (const float*)d_in[0];
    const float* states = (const float*)d_in[1];
    const float* qMax   = (const float*)d_in[2];
    const float* Ro     = (const float*)d_in[3];
    const float* tDiff  = (const float*)d_in[4];
    const float* Wp1    = (const float*)d_in[5];
    const float* bp1    = (const float*)d_in[6];
    const float* Wp2    = (const float*)d_in[7];
    const float* bp2    = (const float*)d_in[8];
    const float* Wp3    = (const float*)d_in[9];
    const float* bp3    = (const float*)d_in[10];
    const float* Wn     = (const float*)d_in[11];
    const float* bn     = (const float*)d_in[12];

    const int n = in_sizes[0];           // B (inputs is (B,1))
    float* outV = (float*)d_out;         // first output: V, B floats
    float* outX = (float*)d_out + n;     // second output: Xnew, B*8 floats

    battery_step_kernel<<<dim3((n + 255) / 256), dim3(256), 0, stream>>>(
        inputs, states, qMax, Ro, tDiff,
        Wp1, bp1, Wp2, bp2, Wp3, bp3, Wn, bn,
        outV, outX, n);
}